// Round 11
// baseline (260.130 us; speedup 1.0000x reference)
//
#include <hip/hip_runtime.h>
#include <stdint.h>

typedef unsigned int u32;
typedef unsigned short u16;
typedef __attribute__((ext_vector_type(8))) short bf16x8;
typedef __attribute__((ext_vector_type(4))) float f32x4;

#define BUF_ELEMS (16384 * 256)

__device__ __forceinline__ float bflo(u32 u) { return __uint_as_float(u << 16); }
__device__ __forceinline__ float bfhi(u32 u) { return __uint_as_float(u & 0xffff0000u); }
__device__ __forceinline__ u16 f2bf(float f) {
    u32 u = __float_as_uint(f);
    return (u16)((u + 0x7fffu + ((u >> 16) & 1u)) >> 16);
}
// pack high halves of two f32 -> u32 (truncation-round bf16 pair, lo first)
__device__ __forceinline__ u32 pkhi(float lo, float hi) {
    return __builtin_amdgcn_perm(__float_as_uint(hi), __float_as_uint(lo), 0x07060302u);
}
// bare v_exp_f32 (2^x) -- avoid OCML denormal-guard fixup around exp2f
__device__ __forceinline__ float fexp2(float x) {
#if __has_builtin(__builtin_amdgcn_exp2f)
    return __builtin_amdgcn_exp2f(x);
#else
    float r; asm("v_exp_f32 %0, %1" : "=v"(r) : "v"(x)); return r;
#endif
}
__device__ __forceinline__ float frcp(float x) {
#if __has_builtin(__builtin_amdgcn_rcpf)
    return __builtin_amdgcn_rcpf(x);
#else
    return 1.f / x;
#endif
}

// ---------------------------------------------------------------------------
// wtrans: 9x W[k][n] fp32 -> Wt[n][k] bf16; block 160 = QKV bias concat;
// blocks 161..176 = inconsistency GEMM + passthroughs (independent work).
// ---------------------------------------------------------------------------
struct WT {
    const float* src[9];
    u16* dst[9];
    const float* bs[6];   // bq_i, bk_t, bv_t, bq_t, bk_i, bv_i
    float* bA;            // [768]
    float* bB;            // [768]
    const float* img_sp;
    const float* txt_sp;
    const float* incw;
    const float* incb;
    float* out_inc;
    float* out_img;
    float* out_txt;
};

__global__ __launch_bounds__(256)
void wtrans_kernel(WT wt)
{
    __shared__ float T[64][65];
    const int bid = blockIdx.x, t = threadIdx.x;
    if (bid == 160) {
        wt.bA[t]       = wt.bs[0][t];
        wt.bA[256 + t] = wt.bs[1][t];
        wt.bA[512 + t] = wt.bs[2][t];
        wt.bB[t]       = wt.bs[3][t];
        wt.bB[256 + t] = wt.bs[4][t];
        wt.bB[512 + t] = wt.bs[5][t];
        return;
    }
    if (bid > 160) {
        float* iv = &T[0][0];
        const int b = bid - 161, n = t;
        float a = wt.img_sp[b * 256 + n];
        float x = wt.txt_sp[b * 256 + n];
        iv[n] = a - x;
        iv[256 + n] = a * x;
        __syncthreads();
        float acc = wt.incb[n];
        for (int k = 0; k < 512; k++) acc += iv[k] * wt.incw[k * 256 + n];
        wt.out_inc[b * 256 + n] = acc;
        wt.out_img[b * 256 + n] = a;
        wt.out_txt[b * 256 + n] = x;
        return;
    }
    int m, sub;
    if (bid < 128) { m = bid >> 4; sub = bid & 15; }
    else           { m = 8;        sub = bid - 128; }
    const int K = (m == 8) ? 512 : 256;
    const int kt = (m == 8) ? (sub & 7) : (sub & 3);
    const int nt = (m == 8) ? (sub >> 3) : (sub >> 2);
    const int k0 = kt * 64, n0 = nt * 64;
    const float* src = wt.src[m];
    u16* dst = wt.dst[m];

    const int kk = t >> 2, nn = (t & 3) * 16;
    #pragma unroll
    for (int j = 0; j < 16; j += 4) {
        float4 v = *(const float4*)(src + (size_t)(k0 + kk) * 256 + n0 + nn + j);
        T[kk][nn + j + 0] = v.x; T[kk][nn + j + 1] = v.y;
        T[kk][nn + j + 2] = v.z; T[kk][nn + j + 3] = v.w;
    }
    __syncthreads();
    const int nn2 = t >> 2, kc = (t & 3) * 16;
    #pragma unroll
    for (int j = 0; j < 16; j++)
        dst[(size_t)(n0 + nn2) * K + k0 + kc + j] = f2bf(T[kc + j][nn2]);
}

// ---------------------------------------------------------------------------
// Unified MFMA GEMM. 128x128 tile, 4 waves (2x2 of 64x64), BK=64.
//  * Register prefetch with NAMED SCALARS (guaranteed VGPRs, rule #20);
//    sched_barrier(0) after load-issue keeps loads ahead of the MFMAs.
//  * bid remap: bid = x + 8*n + 8*c*g (c = #n-tiles), m = x + 8*g: A-panel
//    sharers concurrent + same-XCD -> A from L2.
// MODE 0 QKV : A fp32 img/txt m-stacked (in-register cvt), N=768, K=256,
//              c=6.  Q n-group pre-scaled by 1/sqrt(32)*log2(e).
//              V n-group (n_idx>=4) written TRANSPOSED [b][h][32][1024].
// MODE 1 OPRJ: A bf16, M=32768 m-stacked, N=256, c=2. grid 512.
// MODE 2 ENH : A bf16 x2 kt-concat (K=512), N=256, fp32 out, c=2. grid 256.
// ---------------------------------------------------------------------------
template<int MODE>
__global__ __launch_bounds__(256)
void gemm_mfma(const float* __restrict__ Af0, const float* __restrict__ Af1,
               const u16* __restrict__ Ab0, const u16* __restrict__ Ab1,
               const u16* __restrict__ Wt0, const u16* __restrict__ Wt1,
               const float* __restrict__ bias0, const float* __restrict__ bias1,
               void* __restrict__ o0, void* __restrict__ o1, void* __restrict__ o2,
               void* __restrict__ o3, void* __restrict__ o4, void* __restrict__ o5)
{
    __shared__ u16 As[128][72];
    __shared__ u16 Bs[128][72];
    const int tid = threadIdx.x;
    const int wave = tid >> 6, lane = tid & 63;
    const int L = lane & 15, Qd = lane >> 4;
    // bid = x + 8*n + 8*NC*g ; m = x + 8*g (A-panel sharers concurrent+same-XCD)
    const int NC = (MODE == 0) ? 6 : 2;
    const int x_ = blockIdx.x & 7;
    const int r_ = blockIdx.x >> 3;
    const int n_idx = r_ % NC;
    const int m_idx = x_ + ((r_ / NC) << 3);
    const bool ms = (MODE != 2) && (m_idx >= 128);
    const int lm0 = (MODE == 2) ? m_idx * 128 : (m_idx & 127) * 128;
    const int n0 = n_idx * 128;
    const u16* Wt = ms ? Wt1 : Wt0;
    const float* bias = ms ? bias1 : bias0;
    const int wr = wave & 1, wc = wave >> 1;
    const int sr = tid >> 1, sh = (tid & 1) * 32;
    const int KS = (MODE == 2) ? 512 : 256;

    f32x4 acc[4][4] = {};

    // prefetch registers: NAMED scalars -> guaranteed VGPR allocation
    float4 fr0, fr1, fr2, fr3, fr4, fr5, fr6, fr7;
    uint4  ar0, ar1, ar2, ar3;
    uint4  br0, br1, br2, br3;

    const float* Af = (MODE == 0) ? (ms ? Af1 : Af0) : nullptr;

    auto load_tile = [&](int ktv) {
        if (MODE == 0) {
            const float* Ap = Af + (size_t)(lm0 + sr) * 256 + ktv + sh;
            fr0 = *(const float4*)(Ap + 0);
            fr1 = *(const float4*)(Ap + 4);
            fr2 = *(const float4*)(Ap + 8);
            fr3 = *(const float4*)(Ap + 12);
            fr4 = *(const float4*)(Ap + 16);
            fr5 = *(const float4*)(Ap + 20);
            fr6 = *(const float4*)(Ap + 24);
            fr7 = *(const float4*)(Ap + 28);
        } else {
            const u16* Abase; int lkt = ktv;
            if (MODE == 2) { Abase = (ktv < 256) ? Ab0 : Ab1; lkt = ktv & 255; }
            else           { Abase = ms ? Ab1 : Ab0; }
            const u16* Ap = Abase + (size_t)(lm0 + sr) * 256 + lkt + sh;
            ar0 = *(const uint4*)(Ap + 0);
            ar1 = *(const uint4*)(Ap + 8);
            ar2 = *(const uint4*)(Ap + 16);
            ar3 = *(const uint4*)(Ap + 24);
        }
        const u16* Bp = Wt + (size_t)(n0 + sr) * KS + ktv + sh;
        br0 = *(const uint4*)(Bp + 0);
        br1 = *(const uint4*)(Bp + 8);
        br2 = *(const uint4*)(Bp + 16);
        br3 = *(const uint4*)(Bp + 24);
    };

    auto commit_tile = [&]() {
        if (MODE == 0) {
            uint4 p, q;
            p.x = pkhi(fr0.x, fr0.y); p.y = pkhi(fr0.z, fr0.w);
            p.z = pkhi(fr1.x, fr1.y); p.w = pkhi(fr1.z, fr1.w);
            q.x = pkhi(fr2.x, fr2.y); q.y = pkhi(fr2.z, fr2.w);
            q.z = pkhi(fr3.x, fr3.y); q.w = pkhi(fr3.z, fr3.w);
            *(uint4*)&As[sr][sh + 0] = p;
            *(uint4*)&As[sr][sh + 8] = q;
            p.x = pkhi(fr4.x, fr4.y); p.y = pkhi(fr4.z, fr4.w);
            p.z = pkhi(fr5.x, fr5.y); p.w = pkhi(fr5.z, fr5.w);
            q.x = pkhi(fr6.x, fr6.y); q.y = pkhi(fr6.z, fr6.w);
            q.z = pkhi(fr7.x, fr7.y); q.w = pkhi(fr7.z, fr7.w);
            *(uint4*)&As[sr][sh + 16] = p;
            *(uint4*)&As[sr][sh + 24] = q;
        } else {
            *(uint4*)&As[sr][sh + 0]  = ar0;
            *(uint4*)&As[sr][sh + 8]  = ar1;
            *(uint4*)&As[sr][sh + 16] = ar2;
            *(uint4*)&As[sr][sh + 24] = ar3;
        }
        *(uint4*)&Bs[sr][sh + 0]  = br0;
        *(uint4*)&Bs[sr][sh + 8]  = br1;
        *(uint4*)&Bs[sr][sh + 16] = br2;
        *(uint4*)&Bs[sr][sh + 24] = br3;
    };

    load_tile(0);

    for (int kt = 0; kt < KS; kt += 64) {
        commit_tile();          // vmcnt wait happens here (loads long landed)
        __syncthreads();

        // issue next-tile loads; sched_barrier pins them BEFORE the MFMAs so
        // their latency hides under this tile's compute
        if (kt + 64 < KS) load_tile(kt + 64);
        __builtin_amdgcn_sched_barrier(0);

        #pragma unroll
        for (int kh = 0; kh < 64; kh += 32) {
            bf16x8 af[4], bf[4];
            #pragma unroll
            for (int mt = 0; mt < 4; mt++)
                af[mt] = *(const bf16x8*)&As[wr * 64 + mt * 16 + L][kh + Qd * 8];
            #pragma unroll
            for (int nt = 0; nt < 4; nt++)
                bf[nt] = *(const bf16x8*)&Bs[wc * 64 + nt * 16 + L][kh + Qd * 8];
            #pragma unroll
            for (int mt = 0; mt < 4; mt++)
                #pragma unroll
                for (int nt = 0; nt < 4; nt++)
                    acc[mt][nt] = __builtin_amdgcn_mfma_f32_16x16x32_bf16(
                        af[mt], bf[nt], acc[mt][nt], 0, 0, 0);
        }
        __syncthreads();
    }

    // ---- epilogue ----
    float bvals[4];
    #pragma unroll
    for (int nt = 0; nt < 4; nt++)
        bvals[nt] = bias[n0 + wc * 64 + nt * 16 + L];

    const float qsc = (MODE == 0 && n_idx < 2)
                      ? (0.17677669529663687f * 1.4426950408889634f) : 1.0f;

    void* outp;
    int colb;
    if (MODE == 0) {
        const int g = n_idx >> 1;
        if (!ms) outp = (g == 0) ? o0 : ((g == 1) ? o1 : o2);
        else     outp = (g == 0) ? o3 : ((g == 1) ? o4 : o5);
        colb = (n_idx & 1) * 128 + wc * 64;
    } else if (MODE == 1) {
        outp = ms ? o1 : o0;
        colb = n0 + wc * 64;
    } else {
        outp = o0;
        colb = n0 + wc * 64;
    }

    if (MODE == 0 && n_idx >= 4) {
        // V output, transposed store: V^T[b][h][d][s], s fast (r = token).
        u16* Vg = (u16*)outp;
        #pragma unroll
        for (int mt = 0; mt < 4; mt++) {
            const int tokb = lm0 + wr * 64 + mt * 16 + Qd * 4;   // 4 consecutive tokens (r)
            const int b_ = tokb >> 10;
            const int s_ = tokb & 1023;
            #pragma unroll
            for (int nt = 0; nt < 4; nt++) {
                const int col = colb + nt * 16 + L;              // 0..255
                const int h_ = col >> 5, d_ = col & 31;
                uint2 pk2;
                pk2.x = (u32)f2bf(acc[mt][nt][0] + bvals[nt])
                      | ((u32)f2bf(acc[mt][nt][1] + bvals[nt]) << 16);
                pk2.y = (u32)f2bf(acc[mt][nt][2] + bvals[nt])
                      | ((u32)f2bf(acc[mt][nt][3] + bvals[nt]) << 16);
                *(uint2*)(Vg + ((size_t)((b_ * 8 + h_) * 32 + d_) << 10) + s_) = pk2;
            }
        }
        return;
    }

    #pragma unroll
    for (int mt = 0; mt < 4; mt++) {
        #pragma unroll
        for (int r = 0; r < 4; r++) {
            const size_t row = (size_t)(lm0 + wr * 64 + mt * 16 + Qd * 4 + r) * 256;
            #pragma unroll
            for (int nt = 0; nt < 4; nt++) {
                const int col = colb + nt * 16 + L;
                float v = (acc[mt][nt][r] + bvals[nt]) * qsc;
                if (MODE == 2) ((float*)outp)[row + col] = v;
                else           ((u16*)outp)[row + col] = f2bf(v);
            }
        }
    }
}

// ---------------------------------------------------------------------------
// MFMA flash attention, both sets in one dispatch. 128 q-rows/block (2 qs per
// wave), K-tile 128 keys. grid 2048; block 256.
// bid remap: bid = x + 8*j + 64*g, qt=j (0..7), kv=x+8*g -> the 8 qt-sharers
// of one (set,b,h) are concurrent AND same-XCD -> K/V served from L2.
// Swapped-operand softmax: QK = mfma(A=K, B=Q) so each lane holds P[key][q=L];
// Ks rows sigma-permuted within 32-key blocks so the PV B-fragment is purely
// lane-local; PV is O^T = mfma(A=V^T, B=P); rowsum via mfma(ones, P).
// kc-OUTER / qs-INNER at the 128-q scale (synthesis of rounds 7-10):
//  * each q-invariant kf/vf fragment read ONCE per kc, consumed by 2 qs ->
//    LDS reads/wave/t-iter = 16 frag + 4 staging = 20 (round 7's structure
//    re-read ~32 under its 64-VGPR cap).
//  * named-scalar state (qf0/1, oT00..oT11, oL0/1 + prefetch) ~74 regs
//    combined (VGPR+acc) -> fits the 128-reg 4-waves/SIMD tier; NO second
//    launch-bounds arg (the (256,4) cap caused rounds 8/9 spills; the 256-q
//    variant's 136-reg liveness caused round 10's occupancy drop).
//  * V read from pre-transposed V^T[b][h][32][1024] (written by QKV GEMM).
//  * K/V tile t+1 prefetched into registers while tile t computes.
//  * bare v_exp_f32 / v_rcp_f32; Q pre-scaled -> bare exp2.
// Output in-place over Q.
// ---------------------------------------------------------------------------
__global__ __launch_bounds__(256)
void attn_mfma(const u16* __restrict__ Q0, const u16* __restrict__ K0,
               const u16* __restrict__ V0, u16* __restrict__ O0,
               const u16* __restrict__ Q1, const u16* __restrict__ K1,
               const u16* __restrict__ V1, u16* __restrict__ O1)
{
    __shared__ u16 Ks[128][40];      // [sigma-permuted key row][dim]
    __shared__ u16 Vt[32][136];      // [dim][key]  (physical key order)
    const int tid = threadIdx.x;
    const int wave = tid >> 6, lane = tid & 63;
    const int L = lane & 15, Qd = lane >> 4;
    const int bid = blockIdx.x;
    const int qt = (bid >> 3) & 7;               // 8 qt-sharers: stride-8 window
    const int kv = (bid & 7) | ((bid >> 6) << 3);// same XCD (mod 8) + concurrent
    const int set = kv >> 7;
    const int b = (kv >> 3) & 15;
    const int h = kv & 7;
    const u16* Q = set ? Q1 : Q0;
    const u16* K = set ? K1 : K0;
    const u16* V = set ? V1 : V0;    // V^T layout [b][h][32][1024]
    u16* O = set ? O1 : O0;
    const int rowbase = b * 1024;
    const int qbase = rowbase + qt * 128;

    // q fragments: NAMED (2x bf16x8 = 8 VGPR)
    const u16* qp = Q + (size_t)(qbase + wave * 16 + L) * 256 + h * 32 + Qd * 8;
    bf16x8 qf0 = *(const bf16x8*)(qp + 0 * 64 * 256);
    bf16x8 qf1 = *(const bf16x8*)(qp + 1 * 64 * 256);

    const short oneb = (short)0x3F80;
    const bf16x8 ones = {oneb, oneb, oneb, oneb, oneb, oneb, oneb, oneb};

    // accumulators: NAMED (4x f32x4 O^T + 2x f32x4 rowsum)
    const f32x4 z = {0.f, 0.f, 0.f, 0.f};
    f32x4 oT00 = z, oT01 = z, oT10 = z, oT11 = z;
    f32x4 oL0 = z, oL1 = z;

    // K staging: s = tid>>1 -> kkey bijective, chosen so krow's low bits vary
    // within each 16-lane phase (conflict-free writes).  krow places physical
    // key k at row (k&~31) | sigma(k&31).
    const int s     = tid >> 1;
    const int kkey  = (s & 3) | (((s >> 3) & 1) << 2) | (((s >> 2) & 1) << 3)
                    | (((s >> 4) & 1) << 4) | ((s >> 5) << 5);
    const int kcolh = (tid & 1) * 16;                  // dim half
    const int krow  = (kkey & 96) | (((kkey >> 2) & 1) << 4)
                    | (((kkey >> 3) & 3) << 2) | (kkey & 3);
    const int vd    = tid >> 3;                        // dim 0..31
    const int vkb   = (tid & 7) * 16;                  // key block
    const size_t vplane = (size_t)((b * 8 + h) * 32 + vd) * 1024;

    uint4 kr0, kr1, vr0, vr1;
    {
        const size_t kb = (size_t)(rowbase + kkey) * 256 + h * 32 + kcolh;
        kr0 = *(const uint4*)(K + kb);
        kr1 = *(const uint4*)(K + kb + 8);
        const size_t vb = vplane + vkb;
        vr0 = *(const uint4*)(V + vb);
        vr1 = *(const uint4*)(V + vb + 8);
    }

// per-qs body: QK (swapped), exp2, pack, PV accumulate -- all named state
#define ATTN_QS(QF, OT0, OT1, OL)                                              \
    do {                                                                       \
        f32x4 s0 = __builtin_amdgcn_mfma_f32_16x16x32_bf16(kfA, QF, z, 0, 0, 0); \
        f32x4 s1 = __builtin_amdgcn_mfma_f32_16x16x32_bf16(kfB, QF, z, 0, 0, 0); \
        union { u32 w[4]; bf16x8 v; } pf;                                      \
        pf.w[0] = pkhi(fexp2(s0[0]), fexp2(s0[1]));                            \
        pf.w[1] = pkhi(fexp2(s0[2]), fexp2(s0[3]));                            \
        pf.w[2] = pkhi(fexp2(s1[0]), fexp2(s1[1]));                            \
        pf.w[3] = pkhi(fexp2(s1[2]), fexp2(s1[3]));                            \
        OT0 = __builtin_amdgcn_mfma_f32_16x16x32_bf16(vf0, pf.v, OT0, 0, 0, 0); \
        OT1 = __builtin_amdgcn_mfma_f32_16x16x32_bf16(vf1, pf.v, OT1, 0, 0, 0); \
        OL  = __builtin_amdgcn_mfma_f32_16x16x32_bf16(ones, pf.v, OL, 0, 0, 0); \
    } while (0)

    for (int t = 0; t < 8; t++) {
        // commit prefetched tile to LDS
        *(uint4*)&Ks[krow][kcolh]     = kr0;
        *(uint4*)&Ks[krow][kcolh + 8] = kr1;
        *(uint4*)&Vt[vd][vkb]         = vr0;
        *(uint4*)&Vt[vd][vkb + 8]     = vr1;
        __syncthreads();

        // issue next-tile loads; consumed only after the trailing barrier
        if (t < 7) {
            const size_t kb = (size_t)(rowbase + (t + 1) * 128 + kkey) * 256 + h * 32 + kcolh;
            kr0 = *(const uint4*)(K + kb);
            kr1 = *(const uint4*)(K + kb + 8);
            const size_t vb = vplane + (t + 1) * 128 + vkb;
            vr0 = *(const uint4*)(V + vb);
            vr1 = *(const uint4*)(V + vb + 8);
        }

        // kc OUTER: read each q-invariant fragment once, consume across 2 qs
        #pragma unroll
        for (int kc = 0; kc < 4; kc++) {
            bf16x8 kfA = *(const bf16x8*)&Ks[(2 * kc) * 16 + L][Qd * 8];
            bf16x8 kfB = *(const bf16x8*)&Ks[(2 * kc + 1) * 16 + L][Qd * 8];
            bf16x8 vf0 = *(const bf16x8*)&Vt[L][kc * 32 + Qd * 8];
            bf16x8 vf1 = *(const bf16x8*)&Vt[16 + L][kc * 32 + Qd * 8];
            ATTN_QS(qf0, oT00, oT01, oL0);
            ATTN_QS(qf1, oT10, oT11, oL1);
        }
        __syncthreads();
    }
#undef ATTN_QS

    // epilogue: lane holds O^T[d=db*16+Qd*4+r][q=L]; rows q=L, cols d.
#define ATTN_OUT(QS, OT0, OT1, OL)                                             \
    do {                                                                       \
        float inv = frcp(OL[0]);                                               \
        u16* op = O + (size_t)(qbase + (QS) * 64 + wave * 16 + L) * 256        \
                    + h * 32 + Qd * 4;                                         \
        uint2 w;                                                               \
        w.x = (u32)f2bf(OT0[0] * inv) | ((u32)f2bf(OT0[1] * inv) << 16);       \
        w.y = (u32)f2bf(OT0[2] * inv) | ((u32)f2bf(OT0[3] * inv) << 16);       \
        *(uint2*)(op) = w;                                                     \
        w.x = (u32)f2bf(OT1[0] * inv) | ((u32)f2bf(OT1[1] * inv) << 16);       \
        w.y = (u32)f2bf(OT1[2] * inv) | ((u32)f2bf(OT1[3] * inv) << 16);       \
        *(uint2*)(op + 16) = w;                                                \
    } while (0)

    ATTN_OUT(0, oT00, oT01, oL0);
    ATTN_OUT(1, oT10, oT11, oL1);
#undef ATTN_OUT
}

// ---------------------------------------------------------------------------
// Residual + LayerNorm, both halves in one dispatch.
// ---------------------------------------------------------------------------
__global__ __launch_bounds__(256)
void ln_res_kernel(const u16* __restrict__ P0, const u16* __restrict__ P1,
                   const float* __restrict__ R0, const float* __restrict__ R1,
                   const float* __restrict__ g0, const float* __restrict__ be0,
                   const float* __restrict__ g1, const float* __restrict__ be1,
                   u16* __restrict__ out0, u16* __restrict__ out1)
{
    const int lane = threadIdx.x & 63;
    int row = blockIdx.x * 4 + (threadIdx.x >> 6);
    const bool sel = row >= 16384;
    const u16* P = sel ? P1 : P0;
    const float* R = sel ? R1 : R0;
    const float* g = sel ? g1 : g0;
    const float* be = sel ? be1 : be0;
    u16* out = sel ? out1 : out0;
    if (sel) row -= 16384;
    const int col = lane * 4;
    uint2 pv = *(const uint2*)(P + (size_t)row * 256 + col);
    float4 rv = *(const float4*)(R + (size_t)row * 256 + col);
    float x0 = bflo(pv.x) + rv.x;
    float x1 = bfhi(pv.x) + rv.y;
    float x2 = bflo(pv.y) + rv.z;
    float x3 = bfhi(pv.y) + rv.w;
    float s = x0 + x1 + x2 + x3;
    float s2 = x0*x0 + x1*x1 + x2*x2 + x3*x3;
    #pragma unroll
    for (int off = 32; off > 0; off >>= 1) {
        s  += __shfl_xor(s, off);
        s2 += __shfl_xor(s2, off);
    }
    float mean = s * 0.00390625f;
    float var = fmaxf(s2 * 0.00390625f - mean * mean, 0.f);
    float rstd = rsqrtf(var + 1e-5f);
    float4 gv = *(const float4*)(g + col);
    float4 bv = *(const float4*)(be + col);
    uint2 pk;
    pk.x = (u32)f2bf((x0 - mean) * rstd * gv.x + bv.x)
         | ((u32)f2bf((x1 - mean) * rstd * gv.y + bv.y) << 16);
    pk.y = (u32)f2bf((x2 - mean) * rstd * gv.z + bv.z)
         | ((u32)f2bf((x3 - mean) * rstd * gv.w + bv.w) << 16);
    *(uint2*)(out + (size_t)row * 256 + col) = pk;
}

// ---------------------------------------------------------------------------
extern "C" void kernel_launch(void* const* d_in, const int* in_sizes, int n_in,
                              void* d_out, int out_size, void* d_ws, size_t ws_size,
                              hipStream_t stream)
{
    (void)in_sizes; (void)n_in; (void)out_size; (void)ws_size;
    const float* img    = (const float*)d_in[0];
    const float* txt    = (const float*)d_in[1];
    const float* img_sp = (const float*)d_in[2];
    const float* txt_sp = (const float*)d_in[3];
    const float* wq_i = (const float*)d_in[4];  const float* bq_i = (const float*)d_in[5];
    const float* wk_i = (const float*)d_in[6];  const float* bk_i = (const float*)d_in[7];
    const float* wv_i = (const float*)d_in[8];  const float* bv_i = (const float*)d_in[9];
    const float* wo_i = (const float*)d_in[10]; const float* bo_i = (const float*)d_in[11];
    const float* wq_t = (const float*)d_in[12]; const float* bq_t = (const float*)d_in[13];
    const float* wk_t = (const float*)d_in[14]; const float* bk_t = (const float*)d_in[15];
    const float* wv_t = (const float*)d_in[16]; const float* bv_t = (const float*)d_in[17];
    const float* wo_t = (const float*)d_in[18]; const float* bo_t = (const float*)d_in[19];
    const float* lng_i = (const float*)d_in[20]; const float* lnb_i = (const float*)d_in[21];
    const float* lng_t = (const float*)d_in[22]; const float* lnb_t = (const float*)d_in[23];
    const float* enh_w = (const float*)d_in[24]; const float* enh_b = (const float*)d_in[25];
    const float* incw  = (const float*)d_in[26]; const float* incb  = (const float*)d_in[27];
    float* out = (float*)d_out;
    u16* wsp = (u16*)d_ws;
    u16* B0 = wsp;
    u16* B1 = wsp + 1 * (size_t)BUF_ELEMS;
    u16* B2 = wsp + 2 * (size_t)BUF_ELEMS;
    u16* B3 = wsp + 3 * (size_t)BUF_ELEMS;
    u16* B4 = wsp + 4 * (size_t)BUF_ELEMS;
    u16* B5 = wsp + 5 * (size_t)BUF_ELEMS;
    u16* wbase = wsp + 6 * (size_t)BUF_ELEMS;
    u16* WtA   = wbase;                 // [768][256]: Wq_i^T, Wk_t^T, Wv_t^T
    u16* WtB   = wbase + 196608;        // [768][256]: Wq_t^T, Wk_i^T, Wv_i^T
    u16* Wt_oi = wbase + 393216;
    u16* Wt_ot = wbase + 458752;
    u16* Wt_en = wbase + 524288;        // [256][512]
    float* biasA = (float*)(wbase + 655360);  // [768]
    float* biasB = biasA + 768;

    dim3 blk(256);
    // ---- prep: weights + biases + inconsistency/passthrough ----
    WT wt;
    wt.src[0] = wq_i; wt.dst[0] = WtA;
    wt.src[1] = wk_t; wt.dst[1] = WtA + 65536;
    wt.src[2] = wv_t; wt.dst[2] = WtA + 131072;
    wt.src[3] = wq_t; wt.dst[3] = WtB;
    wt.src[4] = wk_i; wt.dst[4] = WtB + 65536;
    wt.src[5] = wv_i; wt.dst[5] = WtB + 131072;
    wt.src[6] = wo_i; wt.dst[6] = Wt_oi;
    wt.src[7] = wo_t; wt.dst[7] = Wt_ot;
    wt.src[8] = enh_w; wt.dst[8] = Wt_en;
    wt.bs[0] = bq_i; wt.bs[1] = bk_t; wt.bs[2] = bv_t;
    wt.bs[3] = bq_t; wt.bs[4] = bk_i; wt.bs[5] = bv_i;
    wt.bA = biasA; wt.bB = biasB;
    wt.img_sp = img_sp; wt.txt_sp = txt_sp; wt.incw = incw; wt.incb = incb;
    wt.out_inc = out + 4194304; wt.out_img = out + 4198400; wt.out_txt = out + 4202496;
    wtrans_kernel<<<177, blk, 0, stream>>>(wt);

    // ---- merged QKV projections: one dispatch, img+txt M-stacked ----
    // img -> (Q_i2t=B0, K_t2i=B4, V_t2i^T=B5); txt -> (Q_t2i=B3, K_i2t=B1, V_i2t^T=B2)
    gemm_mfma<0><<<1536, blk, 0, stream>>>(img, txt, nullptr, nullptr,
                                           WtA, WtB, biasA, biasB,
                                           B0, B4, B5, B3, B1, B2);
    // ---- both attentions, output in-place over Q (V args are V^T buffers) ----
    attn_mfma<<<2048, blk, 0, stream>>>(B0, B1, B2, B0, B3, B4, B5, B3);
    // ---- output projections, M-stacked ----
    gemm_mfma<1><<<512, blk, 0, stream>>>(nullptr, nullptr, B0, B3,
                                          Wt_oi, Wt_ot, bo_i, bo_t,
                                          B1, B4, nullptr, nullptr, nullptr, nullptr);
    // ---- residual + LN, both halves ----
    ln_res_kernel<<<8192, blk, 0, stream>>>(B1, B4, img, txt,
                                            lng_i, lnb_i, lng_t, lnb_t, B2, B5);
    // ---- enhancement (concat-K, fp32 out) ----
    gemm_mfma<2><<<256, blk, 0, stream>>>(nullptr, nullptr, B2, B5,
                                          Wt_en, nullptr, enh_b, nullptr,
                                          out, nullptr, nullptr, nullptr, nullptr, nullptr);
}

// Round 12
// 252.393 us; speedup vs baseline: 1.0307x; 1.0307x over previous
//
#include <hip/hip_runtime.h>
#include <stdint.h>

typedef unsigned int u32;
typedef unsigned short u16;
typedef __attribute__((ext_vector_type(8))) short bf16x8;
typedef __attribute__((ext_vector_type(4))) float f32x4;

#define BUF_ELEMS (16384 * 256)

__device__ __forceinline__ float bflo(u32 u) { return __uint_as_float(u << 16); }
__device__ __forceinline__ float bfhi(u32 u) { return __uint_as_float(u & 0xffff0000u); }
__device__ __forceinline__ u16 f2bf(float f) {
    u32 u = __float_as_uint(f);
    return (u16)((u + 0x7fffu + ((u >> 16) & 1u)) >> 16);
}
// pack high halves of two f32 -> u32 (truncation-round bf16 pair, lo first)
__device__ __forceinline__ u32 pkhi(float lo, float hi) {
    return __builtin_amdgcn_perm(__float_as_uint(hi), __float_as_uint(lo), 0x07060302u);
}
// bare v_exp_f32 (2^x) -- avoid OCML denormal-guard fixup around exp2f
__device__ __forceinline__ float fexp2(float x) {
#if __has_builtin(__builtin_amdgcn_exp2f)
    return __builtin_amdgcn_exp2f(x);
#else
    float r; asm("v_exp_f32 %0, %1" : "=v"(r) : "v"(x)); return r;
#endif
}
__device__ __forceinline__ float frcp(float x) {
#if __has_builtin(__builtin_amdgcn_rcpf)
    return __builtin_amdgcn_rcpf(x);
#else
    return 1.f / x;
#endif
}

// ---------------------------------------------------------------------------
// wtrans: 9x W[k][n] fp32 -> Wt[n][k] bf16; block 160 = QKV bias concat;
// blocks 161..176 = inconsistency GEMM + passthroughs (independent work).
// ---------------------------------------------------------------------------
struct WT {
    const float* src[9];
    u16* dst[9];
    const float* bs[6];   // bq_i, bk_t, bv_t, bq_t, bk_i, bv_i
    float* bA;            // [768]
    float* bB;            // [768]
    const float* img_sp;
    const float* txt_sp;
    const float* incw;
    const float* incb;
    float* out_inc;
    float* out_img;
    float* out_txt;
};

__global__ __launch_bounds__(256)
void wtrans_kernel(WT wt)
{
    __shared__ float T[64][65];
    const int bid = blockIdx.x, t = threadIdx.x;
    if (bid == 160) {
        wt.bA[t]       = wt.bs[0][t];
        wt.bA[256 + t] = wt.bs[1][t];
        wt.bA[512 + t] = wt.bs[2][t];
        wt.bB[t]       = wt.bs[3][t];
        wt.bB[256 + t] = wt.bs[4][t];
        wt.bB[512 + t] = wt.bs[5][t];
        return;
    }
    if (bid > 160) {
        float* iv = &T[0][0];
        const int b = bid - 161, n = t;
        float a = wt.img_sp[b * 256 + n];
        float x = wt.txt_sp[b * 256 + n];
        iv[n] = a - x;
        iv[256 + n] = a * x;
        __syncthreads();
        float acc = wt.incb[n];
        for (int k = 0; k < 512; k++) acc += iv[k] * wt.incw[k * 256 + n];
        wt.out_inc[b * 256 + n] = acc;
        wt.out_img[b * 256 + n] = a;
        wt.out_txt[b * 256 + n] = x;
        return;
    }
    int m, sub;
    if (bid < 128) { m = bid >> 4; sub = bid & 15; }
    else           { m = 8;        sub = bid - 128; }
    const int K = (m == 8) ? 512 : 256;
    const int kt = (m == 8) ? (sub & 7) : (sub & 3);
    const int nt = (m == 8) ? (sub >> 3) : (sub >> 2);
    const int k0 = kt * 64, n0 = nt * 64;
    const float* src = wt.src[m];
    u16* dst = wt.dst[m];

    const int kk = t >> 2, nn = (t & 3) * 16;
    #pragma unroll
    for (int j = 0; j < 16; j += 4) {
        float4 v = *(const float4*)(src + (size_t)(k0 + kk) * 256 + n0 + nn + j);
        T[kk][nn + j + 0] = v.x; T[kk][nn + j + 1] = v.y;
        T[kk][nn + j + 2] = v.z; T[kk][nn + j + 3] = v.w;
    }
    __syncthreads();
    const int nn2 = t >> 2, kc = (t & 3) * 16;
    #pragma unroll
    for (int j = 0; j < 16; j++)
        dst[(size_t)(n0 + nn2) * K + k0 + kc + j] = f2bf(T[kc + j][nn2]);
}

// ---------------------------------------------------------------------------
// Unified MFMA GEMM. 128x128 tile, 4 waves (2x2 of 64x64), BK=64.
//  * Register prefetch with NAMED SCALARS (guaranteed VGPRs, rule #20);
//    sched_barrier(0) after load-issue keeps loads ahead of the MFMAs.
//  * bid remap: bid = x + 8*n + 8*c*g (c = #n-tiles), m = x + 8*g: A-panel
//    sharers concurrent + same-XCD -> A from L2.
// MODE 0 QKV : A fp32 img/txt m-stacked (in-register cvt), N=768, K=256,
//              c=6.  Q n-group pre-scaled by 1/sqrt(32)*log2(e).
//              V n-group (n_idx>=4) written TRANSPOSED [b][h][32][1024].
// MODE 1 OPRJ: A bf16, M=32768 m-stacked, N=256, c=2. grid 512.
// MODE 2 ENH : A bf16 x2 kt-concat (K=512), N=256, fp32 out, c=2. grid 256.
// ---------------------------------------------------------------------------
template<int MODE>
__global__ __launch_bounds__(256)
void gemm_mfma(const float* __restrict__ Af0, const float* __restrict__ Af1,
               const u16* __restrict__ Ab0, const u16* __restrict__ Ab1,
               const u16* __restrict__ Wt0, const u16* __restrict__ Wt1,
               const float* __restrict__ bias0, const float* __restrict__ bias1,
               void* __restrict__ o0, void* __restrict__ o1, void* __restrict__ o2,
               void* __restrict__ o3, void* __restrict__ o4, void* __restrict__ o5)
{
    __shared__ u16 As[128][72];
    __shared__ u16 Bs[128][72];
    const int tid = threadIdx.x;
    const int wave = tid >> 6, lane = tid & 63;
    const int L = lane & 15, Qd = lane >> 4;
    // bid = x + 8*n + 8*NC*g ; m = x + 8*g (A-panel sharers concurrent+same-XCD)
    const int NC = (MODE == 0) ? 6 : 2;
    const int x_ = blockIdx.x & 7;
    const int r_ = blockIdx.x >> 3;
    const int n_idx = r_ % NC;
    const int m_idx = x_ + ((r_ / NC) << 3);
    const bool ms = (MODE != 2) && (m_idx >= 128);
    const int lm0 = (MODE == 2) ? m_idx * 128 : (m_idx & 127) * 128;
    const int n0 = n_idx * 128;
    const u16* Wt = ms ? Wt1 : Wt0;
    const float* bias = ms ? bias1 : bias0;
    const int wr = wave & 1, wc = wave >> 1;
    const int sr = tid >> 1, sh = (tid & 1) * 32;
    const int KS = (MODE == 2) ? 512 : 256;

    f32x4 acc[4][4] = {};

    // prefetch registers: NAMED scalars -> guaranteed VGPR allocation
    float4 fr0, fr1, fr2, fr3, fr4, fr5, fr6, fr7;
    uint4  ar0, ar1, ar2, ar3;
    uint4  br0, br1, br2, br3;

    const float* Af = (MODE == 0) ? (ms ? Af1 : Af0) : nullptr;

    auto load_tile = [&](int ktv) {
        if (MODE == 0) {
            const float* Ap = Af + (size_t)(lm0 + sr) * 256 + ktv + sh;
            fr0 = *(const float4*)(Ap + 0);
            fr1 = *(const float4*)(Ap + 4);
            fr2 = *(const float4*)(Ap + 8);
            fr3 = *(const float4*)(Ap + 12);
            fr4 = *(const float4*)(Ap + 16);
            fr5 = *(const float4*)(Ap + 20);
            fr6 = *(const float4*)(Ap + 24);
            fr7 = *(const float4*)(Ap + 28);
        } else {
            const u16* Abase; int lkt = ktv;
            if (MODE == 2) { Abase = (ktv < 256) ? Ab0 : Ab1; lkt = ktv & 255; }
            else           { Abase = ms ? Ab1 : Ab0; }
            const u16* Ap = Abase + (size_t)(lm0 + sr) * 256 + lkt + sh;
            ar0 = *(const uint4*)(Ap + 0);
            ar1 = *(const uint4*)(Ap + 8);
            ar2 = *(const uint4*)(Ap + 16);
            ar3 = *(const uint4*)(Ap + 24);
        }
        const u16* Bp = Wt + (size_t)(n0 + sr) * KS + ktv + sh;
        br0 = *(const uint4*)(Bp + 0);
        br1 = *(const uint4*)(Bp + 8);
        br2 = *(const uint4*)(Bp + 16);
        br3 = *(const uint4*)(Bp + 24);
    };

    auto commit_tile = [&]() {
        if (MODE == 0) {
            uint4 p, q;
            p.x = pkhi(fr0.x, fr0.y); p.y = pkhi(fr0.z, fr0.w);
            p.z = pkhi(fr1.x, fr1.y); p.w = pkhi(fr1.z, fr1.w);
            q.x = pkhi(fr2.x, fr2.y); q.y = pkhi(fr2.z, fr2.w);
            q.z = pkhi(fr3.x, fr3.y); q.w = pkhi(fr3.z, fr3.w);
            *(uint4*)&As[sr][sh + 0] = p;
            *(uint4*)&As[sr][sh + 8] = q;
            p.x = pkhi(fr4.x, fr4.y); p.y = pkhi(fr4.z, fr4.w);
            p.z = pkhi(fr5.x, fr5.y); p.w = pkhi(fr5.z, fr5.w);
            q.x = pkhi(fr6.x, fr6.y); q.y = pkhi(fr6.z, fr6.w);
            q.z = pkhi(fr7.x, fr7.y); q.w = pkhi(fr7.z, fr7.w);
            *(uint4*)&As[sr][sh + 16] = p;
            *(uint4*)&As[sr][sh + 24] = q;
        } else {
            *(uint4*)&As[sr][sh + 0]  = ar0;
            *(uint4*)&As[sr][sh + 8]  = ar1;
            *(uint4*)&As[sr][sh + 16] = ar2;
            *(uint4*)&As[sr][sh + 24] = ar3;
        }
        *(uint4*)&Bs[sr][sh + 0]  = br0;
        *(uint4*)&Bs[sr][sh + 8]  = br1;
        *(uint4*)&Bs[sr][sh + 16] = br2;
        *(uint4*)&Bs[sr][sh + 24] = br3;
    };

    load_tile(0);

    for (int kt = 0; kt < KS; kt += 64) {
        commit_tile();          // vmcnt wait happens here (loads long landed)
        __syncthreads();

        // issue next-tile loads; sched_barrier pins them BEFORE the MFMAs so
        // their latency hides under this tile's compute
        if (kt + 64 < KS) load_tile(kt + 64);
        __builtin_amdgcn_sched_barrier(0);

        #pragma unroll
        for (int kh = 0; kh < 64; kh += 32) {
            bf16x8 af[4], bf[4];
            #pragma unroll
            for (int mt = 0; mt < 4; mt++)
                af[mt] = *(const bf16x8*)&As[wr * 64 + mt * 16 + L][kh + Qd * 8];
            #pragma unroll
            for (int nt = 0; nt < 4; nt++)
                bf[nt] = *(const bf16x8*)&Bs[wc * 64 + nt * 16 + L][kh + Qd * 8];
            #pragma unroll
            for (int mt = 0; mt < 4; mt++)
                #pragma unroll
                for (int nt = 0; nt < 4; nt++)
                    acc[mt][nt] = __builtin_amdgcn_mfma_f32_16x16x32_bf16(
                        af[mt], bf[nt], acc[mt][nt], 0, 0, 0);
        }
        __syncthreads();
    }

    // ---- epilogue ----
    float bvals[4];
    #pragma unroll
    for (int nt = 0; nt < 4; nt++)
        bvals[nt] = bias[n0 + wc * 64 + nt * 16 + L];

    const float qsc = (MODE == 0 && n_idx < 2)
                      ? (0.17677669529663687f * 1.4426950408889634f) : 1.0f;

    void* outp;
    int colb;
    if (MODE == 0) {
        const int g = n_idx >> 1;
        if (!ms) outp = (g == 0) ? o0 : ((g == 1) ? o1 : o2);
        else     outp = (g == 0) ? o3 : ((g == 1) ? o4 : o5);
        colb = (n_idx & 1) * 128 + wc * 64;
    } else if (MODE == 1) {
        outp = ms ? o1 : o0;
        colb = n0 + wc * 64;
    } else {
        outp = o0;
        colb = n0 + wc * 64;
    }

    if (MODE == 0 && n_idx >= 4) {
        // V output, transposed store: V^T[b][h][d][s], s fast (r = token).
        u16* Vg = (u16*)outp;
        #pragma unroll
        for (int mt = 0; mt < 4; mt++) {
            const int tokb = lm0 + wr * 64 + mt * 16 + Qd * 4;   // 4 consecutive tokens (r)
            const int b_ = tokb >> 10;
            const int s_ = tokb & 1023;
            #pragma unroll
            for (int nt = 0; nt < 4; nt++) {
                const int col = colb + nt * 16 + L;              // 0..255
                const int h_ = col >> 5, d_ = col & 31;
                uint2 pk2;
                pk2.x = (u32)f2bf(acc[mt][nt][0] + bvals[nt])
                      | ((u32)f2bf(acc[mt][nt][1] + bvals[nt]) << 16);
                pk2.y = (u32)f2bf(acc[mt][nt][2] + bvals[nt])
                      | ((u32)f2bf(acc[mt][nt][3] + bvals[nt]) << 16);
                *(uint2*)(Vg + ((size_t)((b_ * 8 + h_) * 32 + d_) << 10) + s_) = pk2;
            }
        }
        return;
    }

    #pragma unroll
    for (int mt = 0; mt < 4; mt++) {
        #pragma unroll
        for (int r = 0; r < 4; r++) {
            const size_t row = (size_t)(lm0 + wr * 64 + mt * 16 + Qd * 4 + r) * 256;
            #pragma unroll
            for (int nt = 0; nt < 4; nt++) {
                const int col = colb + nt * 16 + L;
                float v = (acc[mt][nt][r] + bvals[nt]) * qsc;
                if (MODE == 2) ((float*)outp)[row + col] = v;
                else           ((u16*)outp)[row + col] = f2bf(v);
            }
        }
    }
}

// ---------------------------------------------------------------------------
// MFMA flash attention, both sets in one dispatch. 128 q-rows/block, K-tile
// 128 keys. grid 2048; block 256.  (round-7 configuration -- best measured:
// 51.0 us, VALUBusy 46%, no spill.)
// bid remap: bid = x + 8*j + 64*g, qt=j, kv=x+8*g -> the 8 qt-sharers of one
// (set,b,h) are concurrent AND same-XCD -> K/V served from L2 (FETCH ideal).
// Swapped-operand softmax: QK = mfma(A=K, B=Q) so each lane holds P[key][q=L];
// Ks rows sigma-permuted within 32-key blocks so the PV B-fragment is purely
// lane-local; PV is O^T = mfma(A=V^T, B=P); rowsum via mfma(ones, P).
// qs-OUTER structure: 8 independent QK MFMAs -> 32 independent exps -> 12 PV
// MFMAs per qs.  This batching gives the best pipe overlap (kc-outer variants
// serialize QK->exp->PV with only 2 MFMAs of ILP; measured slower, r11).
//  * kf[8]/vfr[4][2] hoisted (qs-invariant).
//  * V read from pre-transposed V^T[b][h][32][1024] (written by QKV GEMM).
//  * K/V tile t+1 prefetched into registers while tile t computes.
//  * bare v_exp_f32 / v_rcp_f32; Q pre-scaled -> bare exp2.
// Output in-place over Q.
// ---------------------------------------------------------------------------
__global__ __launch_bounds__(256, 4)
void attn_mfma(const u16* __restrict__ Q0, const u16* __restrict__ K0,
               const u16* __restrict__ V0, u16* __restrict__ O0,
               const u16* __restrict__ Q1, const u16* __restrict__ K1,
               const u16* __restrict__ V1, u16* __restrict__ O1)
{
    __shared__ u16 Ks[128][40];      // [sigma-permuted key row][dim]
    __shared__ u16 Vt[32][136];      // [dim][key]  (physical key order)
    const int tid = threadIdx.x;
    const int wave = tid >> 6, lane = tid & 63;
    const int L = lane & 15, Qd = lane >> 4;
    const int bid = blockIdx.x;
    const int qt = (bid >> 3) & 7;               // 8 qt-sharers: stride-8 window
    const int kv = (bid & 7) | ((bid >> 6) << 3);// same XCD (mod 8) + concurrent
    const int set = kv >> 7;
    const int b = (kv >> 3) & 15;
    const int h = kv & 7;
    const u16* Q = set ? Q1 : Q0;
    const u16* K = set ? K1 : K0;
    const u16* V = set ? V1 : V0;    // V^T layout [b][h][32][1024]
    u16* O = set ? O1 : O0;
    const int rowbase = b * 1024;
    const int qbase = rowbase + qt * 128;

    bf16x8 qfrag[2];
    #pragma unroll
    for (int qs = 0; qs < 2; qs++)
        qfrag[qs] = *(const bf16x8*)(Q + (size_t)(qbase + qs * 64 + wave * 16 + L) * 256
                                       + h * 32 + Qd * 8);

    const short oneb = (short)0x3F80;
    const bf16x8 ones = {oneb, oneb, oneb, oneb, oneb, oneb, oneb, oneb};

    f32x4 oaccT[2][2] = {};   // [qs][dblock]  (O^T: lane holds d=db*16+Qd*4+r, q=L)
    f32x4 oaccL[2] = {};      // rowsum[q=L] broadcast over regs

    // K staging: s = tid>>1 -> kkey bijective, chosen so krow's low bits vary
    // within each 16-lane phase (conflict-free writes).  krow places physical
    // key k at row (k&~31) | sigma(k&31).
    const int s     = tid >> 1;
    const int kkey  = (s & 3) | (((s >> 3) & 1) << 2) | (((s >> 2) & 1) << 3)
                    | (((s >> 4) & 1) << 4) | ((s >> 5) << 5);
    const int kcolh = (tid & 1) * 16;                  // dim half
    const int krow  = (kkey & 96) | (((kkey >> 2) & 1) << 4)
                    | (((kkey >> 3) & 3) << 2) | (kkey & 3);
    const int vd    = tid >> 3;                        // dim 0..31
    const int vkb   = (tid & 7) * 16;                  // key block
    const size_t vplane = (size_t)((b * 8 + h) * 32 + vd) * 1024;

    uint4 kr0, kr1, vr0, vr1;
    {
        const size_t kb = (size_t)(rowbase + kkey) * 256 + h * 32 + kcolh;
        kr0 = *(const uint4*)(K + kb);
        kr1 = *(const uint4*)(K + kb + 8);
        const size_t vb = vplane + vkb;
        vr0 = *(const uint4*)(V + vb);
        vr1 = *(const uint4*)(V + vb + 8);
    }

    for (int t = 0; t < 8; t++) {
        // commit prefetched tile to LDS
        *(uint4*)&Ks[krow][kcolh]     = kr0;
        *(uint4*)&Ks[krow][kcolh + 8] = kr1;
        *(uint4*)&Vt[vd][vkb]         = vr0;
        *(uint4*)&Vt[vd][vkb + 8]     = vr1;
        __syncthreads();

        // issue next-tile loads; consumed only after the trailing barrier
        if (t < 7) {
            const size_t kb = (size_t)(rowbase + (t + 1) * 128 + kkey) * 256 + h * 32 + kcolh;
            kr0 = *(const uint4*)(K + kb);
            kr1 = *(const uint4*)(K + kb + 8);
            const size_t vb = vplane + (t + 1) * 128 + vkb;
            vr0 = *(const uint4*)(V + vb);
            vr1 = *(const uint4*)(V + vb + 8);
        }

        // hoisted K fragments (A-operand; qs-invariant)
        bf16x8 kf[8];
        #pragma unroll
        for (int ct = 0; ct < 8; ct++)
            kf[ct] = *(const bf16x8*)&Ks[ct * 16 + L][Qd * 8];

        // hoisted V^T fragments (A-operand; qs-invariant)
        bf16x8 vfr[4][2];
        #pragma unroll
        for (int kc = 0; kc < 4; kc++) {
            vfr[kc][0] = *(const bf16x8*)&Vt[L][kc * 32 + Qd * 8];
            vfr[kc][1] = *(const bf16x8*)&Vt[16 + L][kc * 32 + Qd * 8];
        }

        #pragma unroll
        for (int qs = 0; qs < 2; qs++) {
            const f32x4 z = {0.f, 0.f, 0.f, 0.f};
            #pragma unroll
            for (int kc = 0; kc < 4; kc++) {
                f32x4 s0 = __builtin_amdgcn_mfma_f32_16x16x32_bf16(kf[2 * kc],     qfrag[qs], z, 0, 0, 0);
                f32x4 s1 = __builtin_amdgcn_mfma_f32_16x16x32_bf16(kf[2 * kc + 1], qfrag[qs], z, 0, 0, 0);
                union { u32 w[4]; bf16x8 v; } pf;
                pf.w[0] = pkhi(fexp2(s0[0]), fexp2(s0[1]));
                pf.w[1] = pkhi(fexp2(s0[2]), fexp2(s0[3]));
                pf.w[2] = pkhi(fexp2(s1[0]), fexp2(s1[1]));
                pf.w[3] = pkhi(fexp2(s1[2]), fexp2(s1[3]));
                oaccT[qs][0] = __builtin_amdgcn_mfma_f32_16x16x32_bf16(vfr[kc][0], pf.v, oaccT[qs][0], 0, 0, 0);
                oaccT[qs][1] = __builtin_amdgcn_mfma_f32_16x16x32_bf16(vfr[kc][1], pf.v, oaccT[qs][1], 0, 0, 0);
                oaccL[qs]    = __builtin_amdgcn_mfma_f32_16x16x32_bf16(ones,       pf.v, oaccL[qs],    0, 0, 0);
            }
        }
        __syncthreads();
    }

    // epilogue: lane holds O^T[d=db*16+Qd*4+r][q=L]; rows q=L, cols d.
    #pragma unroll
    for (int qs = 0; qs < 2; qs++) {
        float inv = frcp(oaccL[qs][0]);
        u16* op = O + (size_t)(qbase + qs * 64 + wave * 16 + L) * 256 + h * 32 + Qd * 4;
        #pragma unroll
        for (int db = 0; db < 2; db++) {
            uint2 w;
            w.x = (u32)f2bf(oaccT[qs][db][0] * inv)
                | ((u32)f2bf(oaccT[qs][db][1] * inv) << 16);
            w.y = (u32)f2bf(oaccT[qs][db][2] * inv)
                | ((u32)f2bf(oaccT[qs][db][3] * inv) << 16);
            *(uint2*)(op + db * 16) = w;
        }
    }
}

// ---------------------------------------------------------------------------
// Residual + LayerNorm, both halves in one dispatch.
// ---------------------------------------------------------------------------
__global__ __launch_bounds__(256)
void ln_res_kernel(const u16* __restrict__ P0, const u16* __restrict__ P1,
                   const float* __restrict__ R0, const float* __restrict__ R1,
                   const float* __restrict__ g0, const float* __restrict__ be0,
                   const float* __restrict__ g1, const float* __restrict__ be1,
                   u16* __restrict__ out0, u16* __restrict__ out1)
{
    const int lane = threadIdx.x & 63;
    int row = blockIdx.x * 4 + (threadIdx.x >> 6);
    const bool sel = row >= 16384;
    const u16* P = sel ? P1 : P0;
    const float* R = sel ? R1 : R0;
    const float* g = sel ? g1 : g0;
    const float* be = sel ? be1 : be0;
    u16* out = sel ? out1 : out0;
    if (sel) row -= 16384;
    const int col = lane * 4;
    uint2 pv = *(const uint2*)(P + (size_t)row * 256 + col);
    float4 rv = *(const float4*)(R + (size_t)row * 256 + col);
    float x0 = bflo(pv.x) + rv.x;
    float x1 = bfhi(pv.x) + rv.y;
    float x2 = bflo(pv.y) + rv.z;
    float x3 = bfhi(pv.y) + rv.w;
    float s = x0 + x1 + x2 + x3;
    float s2 = x0*x0 + x1*x1 + x2*x2 + x3*x3;
    #pragma unroll
    for (int off = 32; off > 0; off >>= 1) {
        s  += __shfl_xor(s, off);
        s2 += __shfl_xor(s2, off);
    }
    float mean = s * 0.00390625f;
    float var = fmaxf(s2 * 0.00390625f - mean * mean, 0.f);
    float rstd = rsqrtf(var + 1e-5f);
    float4 gv = *(const float4*)(g + col);
    float4 bv = *(const float4*)(be + col);
    uint2 pk;
    pk.x = (u32)f2bf((x0 - mean) * rstd * gv.x + bv.x)
         | ((u32)f2bf((x1 - mean) * rstd * gv.y + bv.y) << 16);
    pk.y = (u32)f2bf((x2 - mean) * rstd * gv.z + bv.z)
         | ((u32)f2bf((x3 - mean) * rstd * gv.w + bv.w) << 16);
    *(uint2*)(out + (size_t)row * 256 + col) = pk;
}

// ---------------------------------------------------------------------------
extern "C" void kernel_launch(void* const* d_in, const int* in_sizes, int n_in,
                              void* d_out, int out_size, void* d_ws, size_t ws_size,
                              hipStream_t stream)
{
    (void)in_sizes; (void)n_in; (void)out_size; (void)ws_size;
    const float* img    = (const float*)d_in[0];
    const float* txt    = (const float*)d_in[1];
    const float* img_sp = (const float*)d_in[2];
    const float* txt_sp = (const float*)d_in[3];
    const float* wq_i = (const float*)d_in[4];  const float* bq_i = (const float*)d_in[5];
    const float* wk_i = (const float*)d_in[6];  const float* bk_i = (const float*)d_in[7];
    const float* wv_i = (const float*)d_in[8];  const float* bv_i = (const float*)d_in[9];
    const float* wo_i = (const float*)d_in[10]; const float* bo_i = (const float*)d_in[11];
    const float* wq_t = (const float*)d_in[12]; const float* bq_t = (const float*)d_in[13];
    const float* wk_t = (const float*)d_in[14]; const float* bk_t = (const float*)d_in[15];
    const float* wv_t = (const float*)d_in[16]; const float* bv_t = (const float*)d_in[17];
    const float* wo_t = (const float*)d_in[18]; const float* bo_t = (const float*)d_in[19];
    const float* lng_i = (const float*)d_in[20]; const float* lnb_i = (const float*)d_in[21];
    const float* lng_t = (const float*)d_in[22]; const float* lnb_t = (const float*)d_in[23];
    const float* enh_w = (const float*)d_in[24]; const float* enh_b = (const float*)d_in[25];
    const float* incw  = (const float*)d_in[26]; const float* incb  = (const float*)d_in[27];
    float* out = (float*)d_out;
    u16* wsp = (u16*)d_ws;
    u16* B0 = wsp;
    u16* B1 = wsp + 1 * (size_t)BUF_ELEMS;
    u16* B2 = wsp + 2 * (size_t)BUF_ELEMS;
    u16* B3 = wsp + 3 * (size_t)BUF_ELEMS;
    u16* B4 = wsp + 4 * (size_t)BUF_ELEMS;
    u16* B5 = wsp + 5 * (size_t)BUF_ELEMS;
    u16* wbase = wsp + 6 * (size_t)BUF_ELEMS;
    u16* WtA   = wbase;                 // [768][256]: Wq_i^T, Wk_t^T, Wv_t^T
    u16* WtB   = wbase + 196608;        // [768][256]: Wq_t^T, Wk_i^T, Wv_i^T
    u16* Wt_oi = wbase + 393216;
    u16* Wt_ot = wbase + 458752;
    u16* Wt_en = wbase + 524288;        // [256][512]
    float* biasA = (float*)(wbase + 655360);  // [768]
    float* biasB = biasA + 768;

    dim3 blk(256);
    // ---- prep: weights + biases + inconsistency/passthrough ----
    WT wt;
    wt.src[0] = wq_i; wt.dst[0] = WtA;
    wt.src[1] = wk_t; wt.dst[1] = WtA + 65536;
    wt.src[2] = wv_t; wt.dst[2] = WtA + 131072;
    wt.src[3] = wq_t; wt.dst[3] = WtB;
    wt.src[4] = wk_i; wt.dst[4] = WtB + 65536;
    wt.src[5] = wv_i; wt.dst[5] = WtB + 131072;
    wt.src[6] = wo_i; wt.dst[6] = Wt_oi;
    wt.src[7] = wo_t; wt.dst[7] = Wt_ot;
    wt.src[8] = enh_w; wt.dst[8] = Wt_en;
    wt.bs[0] = bq_i; wt.bs[1] = bk_t; wt.bs[2] = bv_t;
    wt.bs[3] = bq_t; wt.bs[4] = bk_i; wt.bs[5] = bv_i;
    wt.bA = biasA; wt.bB = biasB;
    wt.img_sp = img_sp; wt.txt_sp = txt_sp; wt.incw = incw; wt.incb = incb;
    wt.out_inc = out + 4194304; wt.out_img = out + 4198400; wt.out_txt = out + 4202496;
    wtrans_kernel<<<177, blk, 0, stream>>>(wt);

    // ---- merged QKV projections: one dispatch, img+txt M-stacked ----
    // img -> (Q_i2t=B0, K_t2i=B4, V_t2i^T=B5); txt -> (Q_t2i=B3, K_i2t=B1, V_i2t^T=B2)
    gemm_mfma<0><<<1536, blk, 0, stream>>>(img, txt, nullptr, nullptr,
                                           WtA, WtB, biasA, biasB,
                                           B0, B4, B5, B3, B1, B2);
    // ---- both attentions, output in-place over Q (V args are V^T buffers) ----
    attn_mfma<<<2048, blk, 0, stream>>>(B0, B1, B2, B0, B3, B4, B5, B3);
    // ---- output projections, M-stacked ----
    gemm_mfma<1><<<512, blk, 0, stream>>>(nullptr, nullptr, B0, B3,
                                          Wt_oi, Wt_ot, bo_i, bo_t,
                                          B1, B4, nullptr, nullptr, nullptr, nullptr);
    // ---- residual + LN, both halves ----
    ln_res_kernel<<<8192, blk, 0, stream>>>(B1, B4, img, txt,
                                            lng_i, lnb_i, lng_t, lnb_t, B2, B5);
    // ---- enhancement (concat-K, fp32 out) ----
    gemm_mfma<2><<<256, blk, 0, stream>>>(nullptr, nullptr, B2, B5,
                                          Wt_en, nullptr, enh_b, nullptr,
                                          out, nullptr, nullptr, nullptr, nullptr, nullptr);
}